// Round 1
// baseline (7410.689 us; speedup 1.0000x reference)
//
#include <hip/hip_runtime.h>
#include <hip/hip_bf16.h>

#define L_SEQ 2048
#define BATCH 2
#define DM    1024          // d_model
#define DI    2048          // d_inner
#define DS    16            // d_state
#define DTR   64            // dt_rank
#define DBLC  96            // dt_rank + 2*d_state
#define VOCAB 32000
#define BL    (BATCH * L_SEQ)   // 4096 tokens

// ---------------------------------------------------------------- embedding
__global__ __launch_bounds__(256) void embed_kernel(
    const int* __restrict__ tok, const float* __restrict__ emb,
    float* __restrict__ X)
{
    int row = blockIdx.x;            // 0..BL-1
    int t = tok[row];
    const float4* s = (const float4*)(emb + (size_t)t * DM);
    float4* d = (float4*)(X + (size_t)row * DM);
    d[threadIdx.x] = s[threadIdx.x]; // 256 threads * 4 floats = 1024
}

// ---------------------------------------------------------------- SGEMM
// C[M,N] = A[M,K] * Bt[N,K]^T   (weights stored [out,in] == Bt)
// 128x128 block tile, BK=16, 256 threads, 8x8 micro-tile (split 4+4 at +64
// to keep LDS b128 reads conflict-free).
// EPI: 0 = none, 1 = +bias then softplus
// NGUARD: bounds-check N (for N=96)
// SPLITK: use blockIdx.z chunks of kchunk, write partials C[z][M][ldc]
template<int EPI, bool NGUARD, bool SPLITK>
__global__ __launch_bounds__(256) void sgemm_bt(
    const float* __restrict__ A, int lda,
    const float* __restrict__ Bt, int ldb,
    float* __restrict__ C, int ldc,
    const float* __restrict__ bias,
    int M, int N, int K, int kchunk)
{
    __shared__ float As[16][132];   // +4 pad: 2-way (free) store conflicts,
    __shared__ float Bs[16][132];   // conflict-free b128 reads

    const int tid = threadIdx.x;
    const int bm = blockIdx.y * 128;
    const int bn = blockIdx.x * 128;

    int k0 = 0, kend = K;
    if (SPLITK) {
        k0 = blockIdx.z * kchunk;
        kend = k0 + kchunk; if (kend > K) kend = K;
        C += (size_t)blockIdx.z * (size_t)M * (size_t)ldc;
    }

    const int tx = tid & 15;        // 16 col-groups
    const int ty = tid >> 4;        // 16 row-groups
    const int lr = tid >> 2;        // 0..63 (tile row for loads)
    const int lc = (tid & 3) << 2;  // 0,4,8,12 (k-col for loads)

    float acc[8][8];
#pragma unroll
    for (int i = 0; i < 8; ++i)
#pragma unroll
        for (int j = 0; j < 8; ++j) acc[i][j] = 0.f;

    for (int kk = k0; kk < kend; kk += 16) {
#pragma unroll
        for (int p = 0; p < 2; ++p) {
            int r = lr + p * 64;
            float4 v = *(const float4*)(A + (size_t)(bm + r) * lda + kk + lc);
            As[lc + 0][r] = v.x; As[lc + 1][r] = v.y;
            As[lc + 2][r] = v.z; As[lc + 3][r] = v.w;
        }
#pragma unroll
        for (int p = 0; p < 2; ++p) {
            int r = lr + p * 64;
            float4 v = make_float4(0.f, 0.f, 0.f, 0.f);
            if (!NGUARD || (bn + r) < N)
                v = *(const float4*)(Bt + (size_t)(bn + r) * ldb + kk + lc);
            Bs[lc + 0][r] = v.x; Bs[lc + 1][r] = v.y;
            Bs[lc + 2][r] = v.z; Bs[lc + 3][r] = v.w;
        }
        __syncthreads();
#pragma unroll
        for (int k = 0; k < 16; ++k) {
            float4 a0 = *(const float4*)&As[k][ty * 4];
            float4 a1 = *(const float4*)&As[k][64 + ty * 4];
            float4 b0 = *(const float4*)&Bs[k][tx * 4];
            float4 b1 = *(const float4*)&Bs[k][64 + tx * 4];
            float av[8] = {a0.x, a0.y, a0.z, a0.w, a1.x, a1.y, a1.z, a1.w};
            float bv[8] = {b0.x, b0.y, b0.z, b0.w, b1.x, b1.y, b1.z, b1.w};
#pragma unroll
            for (int i = 0; i < 8; ++i)
#pragma unroll
                for (int j = 0; j < 8; ++j)
                    acc[i][j] += av[i] * bv[j];
        }
        __syncthreads();
    }

    // epilogue: rows bm + p*64 + ty*4 + ii ; cols bn + q*64 + tx*4 + jj
#pragma unroll
    for (int p = 0; p < 2; ++p) {
#pragma unroll
        for (int ii = 0; ii < 4; ++ii) {
            int row = bm + p * 64 + ty * 4 + ii;
#pragma unroll
            for (int q = 0; q < 2; ++q) {
                int col = bn + q * 64 + tx * 4;
                if (NGUARD && col >= N) continue;
                float4 v;
                float* vp = &v.x;
#pragma unroll
                for (int jj = 0; jj < 4; ++jj) {
                    float x = acc[p * 4 + ii][q * 4 + jj];
                    if (EPI == 1) {
                        x += bias[col + jj];
                        x = (x > 20.f) ? x : log1pf(__expf(x));  // softplus
                    }
                    vp[jj] = x;
                }
                *(float4*)(C + (size_t)row * ldc + col) = v;
            }
        }
    }
}

// ---------------------------------------------------------------- split-K reduce
__global__ __launch_bounds__(256) void reduce8_kernel(
    const float* __restrict__ part, float* __restrict__ out, int n)
{
    int i = blockIdx.x * 256 + threadIdx.x;
    if (i < n) {
        float s = 0.f;
#pragma unroll
        for (int j = 0; j < 8; ++j) s += part[(size_t)j * n + i];
        out[i] = s;
    }
}

// ---------------------------------------------------------------- conv + SiLU
// U[row, c] = silu( sum_k XZ[row-3+k, c] * w[c,k] + b[c] ),   c < DI
__global__ __launch_bounds__(256) void conv_silu_kernel(
    const float* __restrict__ XZ, const float* __restrict__ cw,
    const float* __restrict__ cb, float* __restrict__ U)
{
    int idx = blockIdx.x * 256 + threadIdx.x;   // row*512 + c4
    int c4 = idx & 511;
    int row = idx >> 9;
    int t = row & (L_SEQ - 1);
    int c = c4 << 2;

    float4 acc;
    acc.x = cb[c]; acc.y = cb[c + 1]; acc.z = cb[c + 2]; acc.w = cb[c + 3];
    float4 w0 = *(const float4*)(cw + (size_t)(c + 0) * 4);
    float4 w1 = *(const float4*)(cw + (size_t)(c + 1) * 4);
    float4 w2 = *(const float4*)(cw + (size_t)(c + 2) * 4);
    float4 w3 = *(const float4*)(cw + (size_t)(c + 3) * 4);
#pragma unroll
    for (int k = 0; k < 4; ++k) {
        int tt = t - 3 + k;
        if (tt >= 0) {
            float4 xv = *(const float4*)(XZ + (size_t)(row - 3 + k) * (2 * DI) + c);
            acc.x += xv.x * ((&w0.x)[k]);
            acc.y += xv.y * ((&w1.x)[k]);
            acc.z += xv.z * ((&w2.x)[k]);
            acc.w += xv.w * ((&w3.x)[k]);
        }
    }
    // SiLU
    acc.x = acc.x / (1.f + __expf(-acc.x));
    acc.y = acc.y / (1.f + __expf(-acc.y));
    acc.z = acc.z / (1.f + __expf(-acc.z));
    acc.w = acc.w / (1.f + __expf(-acc.w));
    *(float4*)(U + (size_t)row * DI + c) = acc;
}

// ---------------------------------------------------------------- SSM scan
// thread = (channel, state); 16 channels/block; y reduced over 16 lanes.
// Writes final gated output: (ys + u*Dk) * silu(z)
__global__ __launch_bounds__(256) void ssm_scan_kernel(
    const float* __restrict__ U, const float* __restrict__ DELTA,
    const float* __restrict__ DBL, const float* __restrict__ XZ,
    const float* __restrict__ A_log, const float* __restrict__ Dskip,
    float* __restrict__ Y)
{
    int tid = threadIdx.x;
    int s = tid & 15;
    int cl = tid >> 4;
    int ch = blockIdx.x * 16 + cl;   // 0..4095 == b*DI + e
    int b = ch >> 11;                // /DI
    int e = ch & (DI - 1);

    float Ae = -__expf(A_log[(size_t)e * DS + s]);
    float Dk = Dskip[e];
    float h = 0.f;

    const float* up = U     + (size_t)b * L_SEQ * DI + e;
    const float* dp = DELTA + (size_t)b * L_SEQ * DI + e;
    const float* zp = XZ    + (size_t)b * L_SEQ * (2 * DI) + DI + e;
    const float* bp = DBL   + (size_t)b * L_SEQ * DBLC + DTR + s;
    const float* cp = DBL   + (size_t)b * L_SEQ * DBLC + DTR + DS + s;
    float* yp = Y + (size_t)b * L_SEQ * DI + e;

    float u0 = up[0], d0 = dp[0], B0 = bp[0], C0 = cp[0];
    for (int t = 0; t < L_SEQ; ++t) {
        int tn = (t + 1 < L_SEQ) ? t + 1 : t;   // prefetch next (clamped)
        float u1 = up[(size_t)tn * DI];
        float d1 = dp[(size_t)tn * DI];
        float B1 = bp[(size_t)tn * DBLC];
        float C1 = cp[(size_t)tn * DBLC];

        h = h * __expf(d0 * Ae) + d0 * u0 * B0;
        float p = h * C0;
        p += __shfl_xor(p, 1, 16);
        p += __shfl_xor(p, 2, 16);
        p += __shfl_xor(p, 4, 16);
        p += __shfl_xor(p, 8, 16);

        float z = zp[(size_t)t * 2 * DI];
        float g = z / (1.f + __expf(-z));       // silu(z)
        if (s == 0) yp[(size_t)t * DI] = (p + u0 * Dk) * g;

        u0 = u1; d0 = d1; B0 = B1; C0 = C1;
    }
}

// ---------------------------------------------------------------- layernorm
__global__ __launch_bounds__(256) void layernorm_kernel(
    const float* __restrict__ X, const float* __restrict__ g,
    const float* __restrict__ be, float* __restrict__ XN)
{
    __shared__ float red[4];
    int row = blockIdx.x;
    int tid = threadIdx.x;
    float4 v = ((const float4*)(X + (size_t)row * DM))[tid];

    float ssum = v.x + v.y + v.z + v.w;
#pragma unroll
    for (int o = 32; o >= 1; o >>= 1) ssum += __shfl_xor(ssum, o);
    if ((tid & 63) == 0) red[tid >> 6] = ssum;
    __syncthreads();
    float mean = (red[0] + red[1] + red[2] + red[3]) * (1.f / DM);
    __syncthreads();

    float dx = v.x - mean, dy = v.y - mean, dz = v.z - mean, dw = v.w - mean;
    float sq = dx * dx + dy * dy + dz * dz + dw * dw;
#pragma unroll
    for (int o = 32; o >= 1; o >>= 1) sq += __shfl_xor(sq, o);
    if ((tid & 63) == 0) red[tid >> 6] = sq;
    __syncthreads();
    float var = (red[0] + red[1] + red[2] + red[3]) * (1.f / DM);
    float rs = rsqrtf(var + 1e-5f);

    float4 gv = ((const float4*)g)[tid];
    float4 bv = ((const float4*)be)[tid];
    float4 o;
    o.x = dx * rs * gv.x + bv.x;
    o.y = dy * rs * gv.y + bv.y;
    o.z = dz * rs * gv.z + bv.z;
    o.w = dw * rs * gv.w + bv.w;
    ((float4*)(XN + (size_t)row * DM))[tid] = o;
}

// ---------------------------------------------------------------- launch
extern "C" void kernel_launch(void* const* d_in, const int* in_sizes, int n_in,
                              void* d_out, int out_size, void* d_ws, size_t ws_size,
                              hipStream_t stream)
{
    const int*   tokens = (const int*)d_in[0];
    const float* emb    = (const float*)d_in[1];
    const float* in_w   = (const float*)d_in[2];
    const float* conv_w = (const float*)d_in[3];
    const float* conv_b = (const float*)d_in[4];
    const float* xp_w   = (const float*)d_in[5];
    const float* dt_w   = (const float*)d_in[6];
    const float* dt_b   = (const float*)d_in[7];
    const float* A_log  = (const float*)d_in[8];
    const float* Dskip  = (const float*)d_in[9];
    const float* out_w  = (const float*)d_in[10];
    const float* gamma  = (const float*)d_in[11];
    const float* beta   = (const float*)d_in[12];
    const float* lm_w   = (const float*)d_in[13];
    float* out = (float*)d_out;

    float* ws = (float*)d_ws;
    size_t off = 0;
    float* X     = ws + off; off += (size_t)BL * DM;        // 4.19M
    float* XZ    = ws + off; off += (size_t)BL * 2 * DI;    // 16.78M
    float* U     = ws + off; off += (size_t)BL * DI;        // 8.39M
    float* DBL   = ws + off; off += (size_t)BL * DBLC;      // 0.39M
    float* DELTA = ws + off; off += (size_t)BL * DI;        // 8.39M
    float* Y     = ws + off; off += (size_t)BL * DI;        // 8.39M
    float* PART  = DELTA;   // split-K partials (8*BL*96 = 3.1M < 8.39M), dead
                            // before dt_proj writes DELTA
    float* XN    = XZ;      // XZ dead after layer-2 scan; LN output aliases it

    embed_kernel<<<BL, 256, 0, stream>>>(tokens, emb, X);

    for (int l = 0; l < 2; ++l) {
        const float* iw  = in_w   + (size_t)l * 2 * DI * DM;
        const float* cwp = conv_w + (size_t)l * DI * 4;
        const float* cbp = conv_b + (size_t)l * DI;
        const float* xw  = xp_w   + (size_t)l * DBLC * DI;
        const float* dw  = dt_w   + (size_t)l * DI * DTR;
        const float* dbp = dt_b   + (size_t)l * DI;
        const float* alp = A_log  + (size_t)l * DI * DS;
        const float* dkp = Dskip  + (size_t)l * DI;
        const float* ow  = out_w  + (size_t)l * DM * DI;

        // xz = x @ in_w^T : [4096,4096]
        sgemm_bt<0, false, false><<<dim3(32, 32), 256, 0, stream>>>(
            X, DM, iw, DM, XZ, 2 * DI, nullptr, BL, 2 * DI, DM, 0);
        // u = silu(conv(xz[:, :DI]))
        conv_silu_kernel<<<(BL * DI / 4) / 256, 256, 0, stream>>>(XZ, cwp, cbp, U);
        // x_dbl = u @ xp_w^T : [4096,96]  (split-K=8 + reduce)
        sgemm_bt<0, true, true><<<dim3(1, 32, 8), 256, 0, stream>>>(
            U, DI, xw, DI, PART, DBLC, nullptr, BL, DBLC, DI, DI / 8);
        reduce8_kernel<<<(BL * DBLC + 255) / 256, 256, 0, stream>>>(
            PART, DBL, BL * DBLC);
        // delta = softplus(dt @ dt_w^T + dt_b) : [4096,2048]
        sgemm_bt<1, false, false><<<dim3(16, 32), 256, 0, stream>>>(
            DBL, DBLC, dw, DTR, DELTA, DI, dbp, BL, DI, DTR, 0);
        // scan + D-skip + gating
        ssm_scan_kernel<<<BL / 16, 256, 0, stream>>>(
            U, DELTA, DBL, XZ, alp, dkp, Y);
        // x = y @ out_w^T : [4096,1024]
        sgemm_bt<0, false, false><<<dim3(8, 32), 256, 0, stream>>>(
            Y, DI, ow, DI, X, DM, nullptr, BL, DM, DI, 0);
    }

    layernorm_kernel<<<BL, 256, 0, stream>>>(X, gamma, beta, XN);
    // logits = xn @ lm_head^T : [4096,32000]
    sgemm_bt<0, false, false><<<dim3(VOCAB / 128, 32), 256, 0, stream>>>(
        XN, DM, lm_w, DM, out, VOCAB, nullptr, BL, VOCAB, DM, 0);
}

// Round 2
// 2443.409 us; speedup vs baseline: 3.0329x; 3.0329x over previous
//
#include <hip/hip_runtime.h>
#include <hip/hip_bf16.h>

#define L_SEQ 2048
#define BATCH 2
#define DM    1024          // d_model
#define DI    2048          // d_inner
#define DS    16            // d_state
#define DTR   64            // dt_rank
#define DBLC  96            // dt_rank + 2*d_state
#define VOCAB 32000
#define BL    (BATCH * L_SEQ)   // 4096 tokens

typedef short s8v  __attribute__((ext_vector_type(8)));
typedef float f32x4 __attribute__((ext_vector_type(4)));

// round-to-nearest-even fp32 -> bf16
static __device__ __forceinline__ unsigned short f2bf(float f) {
    unsigned u = __builtin_bit_cast(unsigned, f);
    u += 0x7fffu + ((u >> 16) & 1u);
    return (unsigned short)(u >> 16);
}

// ---------------------------------------------------------------- embedding
__global__ __launch_bounds__(256) void embed_kernel(
    const int* __restrict__ tok, const float* __restrict__ emb,
    float* __restrict__ X)
{
    int row = blockIdx.x;
    int t = tok[row];
    const float4* s = (const float4*)(emb + (size_t)t * DM);
    float4* d = (float4*)(X + (size_t)row * DM);
    d[threadIdx.x] = s[threadIdx.x];
}

// ---------------------------------------------------------------- bf16 MFMA GEMM
// C[M,N] = A[M,K] * Bt[N,K]^T, fp32 in/out, bf16 MFMA compute.
// 128x128 tile, BK=32, 256 threads = 4 waves (2x2), wave tile 64x64 =
// 4x4 frags of mfma_f32_16x16x32_bf16. fp32->bf16 conversion during
// reg-staging. LDS slot-swizzle: slot(k>>3) ^= (row>>1)&3 -> fragment
// ds_read_b128 touches each bank exactly 8x per wave (theoretical min).
__global__ __launch_bounds__(256) void gemm_bf16(
    const float* __restrict__ A, int lda,
    const float* __restrict__ Bt, int ldb,
    float* __restrict__ C, int ldc,
    int M, int N, int K)
{
    __shared__ __align__(16) unsigned short As[128 * 32];
    __shared__ __align__(16) unsigned short Bs[128 * 32];

    const int tid = threadIdx.x;
    const int bm = blockIdx.y * 128;
    const int bn = blockIdx.x * 128;

    // staging coords: thread t -> row t>>1, k-offset (t&1)*16 (16 floats)
    const int srow = tid >> 1;
    const int skb  = (tid & 1) * 16;
    const int sg   = (srow >> 1) & 3;                 // swizzle group
    const int sidx0 = srow * 32 + (((skb >> 3) + 0) ^ sg) * 8;
    const int sidx1 = srow * 32 + (((skb >> 3) + 1) ^ sg) * 8;

    // fragment coords
    const int lane = tid & 63;
    const int wv = tid >> 6;
    const int wr = (wv >> 1) * 64;
    const int wc = (wv & 1) * 64;
    const int li = lane & 15;
    const int kc = lane >> 4;                          // k-slot 0..3
    const int fs = (kc ^ ((li >> 1) & 3)) * 8;         // swizzled slot elems

    f32x4 acc[4][4];
#pragma unroll
    for (int m = 0; m < 4; ++m)
#pragma unroll
        for (int n = 0; n < 4; ++n) acc[m][n] = (f32x4)0.f;

    const float* ap = A + (size_t)(bm + srow) * lda + skb;
    const float* bp = Bt + (size_t)(bn + srow) * ldb + skb;

    for (int kk = 0; kk < K; kk += 32) {
        float4 av0 = *(const float4*)(ap + kk);
        float4 av1 = *(const float4*)(ap + kk + 4);
        float4 av2 = *(const float4*)(ap + kk + 8);
        float4 av3 = *(const float4*)(ap + kk + 12);
        float4 bv0 = *(const float4*)(bp + kk);
        float4 bv1 = *(const float4*)(bp + kk + 4);
        float4 bv2 = *(const float4*)(bp + kk + 8);
        float4 bv3 = *(const float4*)(bp + kk + 12);

        unsigned short aw[16], bw[16];
        const float* af = &av0.x;  // av0..av3 contiguous? not guaranteed; do explicit
        aw[0]=f2bf(av0.x); aw[1]=f2bf(av0.y); aw[2]=f2bf(av0.z); aw[3]=f2bf(av0.w);
        aw[4]=f2bf(av1.x); aw[5]=f2bf(av1.y); aw[6]=f2bf(av1.z); aw[7]=f2bf(av1.w);
        aw[8]=f2bf(av2.x); aw[9]=f2bf(av2.y); aw[10]=f2bf(av2.z); aw[11]=f2bf(av2.w);
        aw[12]=f2bf(av3.x); aw[13]=f2bf(av3.y); aw[14]=f2bf(av3.z); aw[15]=f2bf(av3.w);
        bw[0]=f2bf(bv0.x); bw[1]=f2bf(bv0.y); bw[2]=f2bf(bv0.z); bw[3]=f2bf(bv0.w);
        bw[4]=f2bf(bv1.x); bw[5]=f2bf(bv1.y); bw[6]=f2bf(bv1.z); bw[7]=f2bf(bv1.w);
        bw[8]=f2bf(bv2.x); bw[9]=f2bf(bv2.y); bw[10]=f2bf(bv2.z); bw[11]=f2bf(bv2.w);
        bw[12]=f2bf(bv3.x); bw[13]=f2bf(bv3.y); bw[14]=f2bf(bv3.z); bw[15]=f2bf(bv3.w);
        (void)af;

        *(s8v*)&As[sidx0] = *(s8v*)&aw[0];
        *(s8v*)&As[sidx1] = *(s8v*)&aw[8];
        *(s8v*)&Bs[sidx0] = *(s8v*)&bw[0];
        *(s8v*)&Bs[sidx1] = *(s8v*)&bw[8];
        __syncthreads();

        s8v afr[4], bfr[4];
#pragma unroll
        for (int m = 0; m < 4; ++m)
            afr[m] = *(const s8v*)&As[(wr + m * 16 + li) * 32 + fs];
#pragma unroll
        for (int n = 0; n < 4; ++n)
            bfr[n] = *(const s8v*)&Bs[(wc + n * 16 + li) * 32 + fs];
#pragma unroll
        for (int m = 0; m < 4; ++m)
#pragma unroll
            for (int n = 0; n < 4; ++n)
                acc[m][n] = __builtin_amdgcn_mfma_f32_16x16x32_bf16(
                    afr[m], bfr[n], acc[m][n], 0, 0, 0);
        __syncthreads();
    }

    // C row = bm+wr+m*16+kc*4+j, col = bn+wc+n*16+li
#pragma unroll
    for (int m = 0; m < 4; ++m) {
#pragma unroll
        for (int j = 0; j < 4; ++j) {
            int row = bm + wr + m * 16 + kc * 4 + j;
            float* cr = C + (size_t)row * ldc + bn + wc + li;
#pragma unroll
            for (int n = 0; n < 4; ++n)
                cr[n * 16] = acc[m][n][j];
        }
    }
}

// ---------------------------------------------------------------- fp32 SGEMM (small)
template<int EPI, bool NGUARD, bool SPLITK>
__global__ __launch_bounds__(256) void sgemm_bt(
    const float* __restrict__ A, int lda,
    const float* __restrict__ Bt, int ldb,
    float* __restrict__ C, int ldc,
    const float* __restrict__ bias,
    int M, int N, int K, int kchunk)
{
    __shared__ float As[16][132];
    __shared__ float Bs[16][132];

    const int tid = threadIdx.x;
    const int bm = blockIdx.y * 128;
    const int bn = blockIdx.x * 128;

    int k0 = 0, kend = K;
    if (SPLITK) {
        k0 = blockIdx.z * kchunk;
        kend = k0 + kchunk; if (kend > K) kend = K;
        C += (size_t)blockIdx.z * (size_t)M * (size_t)ldc;
    }

    const int tx = tid & 15;
    const int ty = tid >> 4;
    const int lr = tid >> 2;
    const int lc = (tid & 3) << 2;

    float acc[8][8];
#pragma unroll
    for (int i = 0; i < 8; ++i)
#pragma unroll
        for (int j = 0; j < 8; ++j) acc[i][j] = 0.f;

    for (int kk = k0; kk < kend; kk += 16) {
#pragma unroll
        for (int p = 0; p < 2; ++p) {
            int r = lr + p * 64;
            float4 v = *(const float4*)(A + (size_t)(bm + r) * lda + kk + lc);
            As[lc + 0][r] = v.x; As[lc + 1][r] = v.y;
            As[lc + 2][r] = v.z; As[lc + 3][r] = v.w;
        }
#pragma unroll
        for (int p = 0; p < 2; ++p) {
            int r = lr + p * 64;
            float4 v = make_float4(0.f, 0.f, 0.f, 0.f);
            if (!NGUARD || (bn + r) < N)
                v = *(const float4*)(Bt + (size_t)(bn + r) * ldb + kk + lc);
            Bs[lc + 0][r] = v.x; Bs[lc + 1][r] = v.y;
            Bs[lc + 2][r] = v.z; Bs[lc + 3][r] = v.w;
        }
        __syncthreads();
#pragma unroll
        for (int k = 0; k < 16; ++k) {
            float4 a0 = *(const float4*)&As[k][ty * 4];
            float4 a1 = *(const float4*)&As[k][64 + ty * 4];
            float4 b0 = *(const float4*)&Bs[k][tx * 4];
            float4 b1 = *(const float4*)&Bs[k][64 + tx * 4];
            float av[8] = {a0.x, a0.y, a0.z, a0.w, a1.x, a1.y, a1.z, a1.w};
            float bv[8] = {b0.x, b0.y, b0.z, b0.w, b1.x, b1.y, b1.z, b1.w};
#pragma unroll
            for (int i = 0; i < 8; ++i)
#pragma unroll
                for (int j = 0; j < 8; ++j)
                    acc[i][j] += av[i] * bv[j];
        }
        __syncthreads();
    }

#pragma unroll
    for (int p = 0; p < 2; ++p) {
#pragma unroll
        for (int ii = 0; ii < 4; ++ii) {
            int row = bm + p * 64 + ty * 4 + ii;
#pragma unroll
            for (int q = 0; q < 2; ++q) {
                int col = bn + q * 64 + tx * 4;
                if (NGUARD && col >= N) continue;
                float4 v;
                float* vp = &v.x;
#pragma unroll
                for (int jj = 0; jj < 4; ++jj) {
                    float x = acc[p * 4 + ii][q * 4 + jj];
                    if (EPI == 1) {
                        x += bias[col + jj];
                        x = (x > 20.f) ? x : log1pf(__expf(x));
                    }
                    vp[jj] = x;
                }
                *(float4*)(C + (size_t)row * ldc + col) = v;
            }
        }
    }
}

// ---------------------------------------------------------------- split-K reduce
__global__ __launch_bounds__(256) void reduce8_kernel(
    const float* __restrict__ part, float* __restrict__ out, int n)
{
    int i = blockIdx.x * 256 + threadIdx.x;
    if (i < n) {
        float s = 0.f;
#pragma unroll
        for (int j = 0; j < 8; ++j) s += part[(size_t)j * n + i];
        out[i] = s;
    }
}

// ---------------------------------------------------------------- conv + SiLU
__global__ __launch_bounds__(256) void conv_silu_kernel(
    const float* __restrict__ XZ, const float* __restrict__ cw,
    const float* __restrict__ cb, float* __restrict__ U)
{
    int idx = blockIdx.x * 256 + threadIdx.x;
    int c4 = idx & 511;
    int row = idx >> 9;
    int t = row & (L_SEQ - 1);
    int c = c4 << 2;

    float4 acc;
    acc.x = cb[c]; acc.y = cb[c + 1]; acc.z = cb[c + 2]; acc.w = cb[c + 3];
    float4 w0 = *(const float4*)(cw + (size_t)(c + 0) * 4);
    float4 w1 = *(const float4*)(cw + (size_t)(c + 1) * 4);
    float4 w2 = *(const float4*)(cw + (size_t)(c + 2) * 4);
    float4 w3 = *(const float4*)(cw + (size_t)(c + 3) * 4);
#pragma unroll
    for (int k = 0; k < 4; ++k) {
        int tt = t - 3 + k;
        if (tt >= 0) {
            float4 xv = *(const float4*)(XZ + (size_t)(row - 3 + k) * (2 * DI) + c);
            acc.x += xv.x * ((&w0.x)[k]);
            acc.y += xv.y * ((&w1.x)[k]);
            acc.z += xv.z * ((&w2.x)[k]);
            acc.w += xv.w * ((&w3.x)[k]);
        }
    }
    acc.x = acc.x / (1.f + __expf(-acc.x));
    acc.y = acc.y / (1.f + __expf(-acc.y));
    acc.z = acc.z / (1.f + __expf(-acc.z));
    acc.w = acc.w / (1.f + __expf(-acc.w));
    *(float4*)(U + (size_t)row * DI + c) = acc;
}

// ---------------------------------------------------------------- SSM scan
// thread = (channel, state); depth-8 register prefetch ring (static idx).
__global__ __launch_bounds__(256) void ssm_scan_kernel(
    const float* __restrict__ U, const float* __restrict__ DELTA,
    const float* __restrict__ DBL, const float* __restrict__ XZ,
    const float* __restrict__ A_log, const float* __restrict__ Dskip,
    float* __restrict__ Y)
{
    int tid = threadIdx.x;
    int s = tid & 15;
    int cl = tid >> 4;
    int ch = blockIdx.x * 16 + cl;
    int b = ch >> 11;
    int e = ch & (DI - 1);

    float Ae = -__expf(A_log[(size_t)e * DS + s]);
    float Dk = Dskip[e];
    float h = 0.f;

    const float* up = U     + (size_t)b * L_SEQ * DI + e;
    const float* dp = DELTA + (size_t)b * L_SEQ * DI + e;
    const float* zp = XZ    + (size_t)b * L_SEQ * (2 * DI) + DI + e;
    const float* bp = DBL   + (size_t)b * L_SEQ * DBLC + DTR + s;
    const float* cp = DBL   + (size_t)b * L_SEQ * DBLC + DTR + DS + s;
    float* yp = Y + (size_t)b * L_SEQ * DI + e;

    float u[8], d[8], Bv[8], Cv[8], zv[8];
#pragma unroll
    for (int j = 0; j < 8; ++j) {
        u[j]  = up[(size_t)j * DI];
        d[j]  = dp[(size_t)j * DI];
        Bv[j] = bp[(size_t)j * DBLC];
        Cv[j] = cp[(size_t)j * DBLC];
        zv[j] = zp[(size_t)j * 2 * DI];
    }

    for (int t0 = 0; t0 < L_SEQ; t0 += 8) {
        float nu[8], nd[8], nB[8], nC[8], nz[8];
        if (t0 + 8 < L_SEQ) {
#pragma unroll
            for (int j = 0; j < 8; ++j) {
                size_t tt = (size_t)(t0 + 8 + j);
                nu[j] = up[tt * DI];
                nd[j] = dp[tt * DI];
                nB[j] = bp[tt * DBLC];
                nC[j] = cp[tt * DBLC];
                nz[j] = zp[tt * 2 * DI];
            }
        } else {
#pragma unroll
            for (int j = 0; j < 8; ++j) { nu[j]=nd[j]=nB[j]=nC[j]=nz[j]=0.f; }
        }
#pragma unroll
        for (int j = 0; j < 8; ++j) {
            h = h * __expf(d[j] * Ae) + d[j] * u[j] * Bv[j];
            float p = h * Cv[j];
            p += __shfl_xor(p, 1, 16);
            p += __shfl_xor(p, 2, 16);
            p += __shfl_xor(p, 4, 16);
            p += __shfl_xor(p, 8, 16);
            float g = zv[j] / (1.f + __expf(-zv[j]));
            if (s == 0) yp[(size_t)(t0 + j) * DI] = (p + u[j] * Dk) * g;
        }
#pragma unroll
        for (int j = 0; j < 8; ++j) {
            u[j] = nu[j]; d[j] = nd[j]; Bv[j] = nB[j]; Cv[j] = nC[j]; zv[j] = nz[j];
        }
    }
}

// ---------------------------------------------------------------- layernorm
__global__ __launch_bounds__(256) void layernorm_kernel(
    const float* __restrict__ X, const float* __restrict__ g,
    const float* __restrict__ be, float* __restrict__ XN)
{
    __shared__ float red[4];
    int row = blockIdx.x;
    int tid = threadIdx.x;
    float4 v = ((const float4*)(X + (size_t)row * DM))[tid];

    float ssum = v.x + v.y + v.z + v.w;
#pragma unroll
    for (int o = 32; o >= 1; o >>= 1) ssum += __shfl_xor(ssum, o);
    if ((tid & 63) == 0) red[tid >> 6] = ssum;
    __syncthreads();
    float mean = (red[0] + red[1] + red[2] + red[3]) * (1.f / DM);
    __syncthreads();

    float dx = v.x - mean, dy = v.y - mean, dz = v.z - mean, dw = v.w - mean;
    float sq = dx * dx + dy * dy + dz * dz + dw * dw;
#pragma unroll
    for (int o = 32; o >= 1; o >>= 1) sq += __shfl_xor(sq, o);
    if ((tid & 63) == 0) red[tid >> 6] = sq;
    __syncthreads();
    float var = (red[0] + red[1] + red[2] + red[3]) * (1.f / DM);
    float rs = rsqrtf(var + 1e-5f);

    float4 gv = ((const float4*)g)[tid];
    float4 bv = ((const float4*)be)[tid];
    float4 o;
    o.x = dx * rs * gv.x + bv.x;
    o.y = dy * rs * gv.y + bv.y;
    o.z = dz * rs * gv.z + bv.z;
    o.w = dw * rs * gv.w + bv.w;
    ((float4*)(XN + (size_t)row * DM))[tid] = o;
}

// ---------------------------------------------------------------- launch
extern "C" void kernel_launch(void* const* d_in, const int* in_sizes, int n_in,
                              void* d_out, int out_size, void* d_ws, size_t ws_size,
                              hipStream_t stream)
{
    const int*   tokens = (const int*)d_in[0];
    const float* emb    = (const float*)d_in[1];
    const float* in_w   = (const float*)d_in[2];
    const float* conv_w = (const float*)d_in[3];
    const float* conv_b = (const float*)d_in[4];
    const float* xp_w   = (const float*)d_in[5];
    const float* dt_w   = (const float*)d_in[6];
    const float* dt_b   = (const float*)d_in[7];
    const float* A_log  = (const float*)d_in[8];
    const float* Dskip  = (const float*)d_in[9];
    const float* out_w  = (const float*)d_in[10];
    const float* gamma  = (const float*)d_in[11];
    const float* beta   = (const float*)d_in[12];
    const float* lm_w   = (const float*)d_in[13];
    float* out = (float*)d_out;

    float* ws = (float*)d_ws;
    size_t off = 0;
    float* X     = ws + off; off += (size_t)BL * DM;
    float* XZ    = ws + off; off += (size_t)BL * 2 * DI;
    float* U     = ws + off; off += (size_t)BL * DI;
    float* DBL   = ws + off; off += (size_t)BL * DBLC;
    float* DELTA = ws + off; off += (size_t)BL * DI;
    float* Y     = ws + off; off += (size_t)BL * DI;
    float* PART  = DELTA;   // split-K partials, dead before dt_proj writes DELTA
    float* XN    = XZ;      // XZ dead after layer-2 scan

    embed_kernel<<<BL, 256, 0, stream>>>(tokens, emb, X);

    for (int l = 0; l < 2; ++l) {
        const float* iw  = in_w   + (size_t)l * 2 * DI * DM;
        const float* cwp = conv_w + (size_t)l * DI * 4;
        const float* cbp = conv_b + (size_t)l * DI;
        const float* xw  = xp_w   + (size_t)l * DBLC * DI;
        const float* dw  = dt_w   + (size_t)l * DI * DTR;
        const float* dbp = dt_b   + (size_t)l * DI;
        const float* alp = A_log  + (size_t)l * DI * DS;
        const float* dkp = Dskip  + (size_t)l * DI;
        const float* ow  = out_w  + (size_t)l * DM * DI;

        // xz = x @ in_w^T : [4096,4096], K=1024 (bf16 MFMA)
        gemm_bf16<<<dim3(32, 32), 256, 0, stream>>>(
            X, DM, iw, DM, XZ, 2 * DI, BL, 2 * DI, DM);
        // u = silu(conv(xz[:, :DI]))
        conv_silu_kernel<<<(BL * DI / 4) / 256, 256, 0, stream>>>(XZ, cwp, cbp, U);
        // x_dbl = u @ xp_w^T : [4096,96] fp32 split-K
        sgemm_bt<0, true, true><<<dim3(1, 32, 8), 256, 0, stream>>>(
            U, DI, xw, DI, PART, DBLC, nullptr, BL, DBLC, DI, DI / 8);
        reduce8_kernel<<<(BL * DBLC + 255) / 256, 256, 0, stream>>>(
            PART, DBL, BL * DBLC);
        // delta = softplus(dt @ dt_w^T + dt_b) fp32 (K=64)
        sgemm_bt<1, false, false><<<dim3(16, 32), 256, 0, stream>>>(
            DBL, DBLC, dw, DTR, DELTA, DI, dbp, BL, DI, DTR, 0);
        // scan + D-skip + gating
        ssm_scan_kernel<<<BL / 16, 256, 0, stream>>>(
            U, DELTA, DBL, XZ, alp, dkp, Y);
        // x = y @ out_w^T : [4096,1024], K=2048 (bf16 MFMA)
        gemm_bf16<<<dim3(8, 32), 256, 0, stream>>>(
            Y, DI, ow, DI, X, DM, BL, DM, DI);
    }

    layernorm_kernel<<<BL, 256, 0, stream>>>(X, gamma, beta, XN);
    // logits = xn @ lm_head^T : [4096,32000], K=1024 (bf16 MFMA)
    gemm_bf16<<<dim3(VOCAB / 128, 32), 256, 0, stream>>>(
        XN, DM, lm_w, DM, out, VOCAB, BL, VOCAB, DM);
}

// Round 4
// 2043.007 us; speedup vs baseline: 3.6273x; 1.1960x over previous
//
#include <hip/hip_runtime.h>
#include <hip/hip_bf16.h>

#define L_SEQ 2048
#define BATCH 2
#define DM    1024          // d_model
#define DI    2048          // d_inner
#define DS    16            // d_state
#define DTR   64            // dt_rank
#define DBLC  96            // dt_rank + 2*d_state
#define VOCAB 32000
#define BL    (BATCH * L_SEQ)   // 4096 tokens

typedef unsigned short u16;
typedef short s8v  __attribute__((ext_vector_type(8)));   // 8 bf16
typedef float f32x4 __attribute__((ext_vector_type(4)));

typedef __attribute__((address_space(1))) const void* as1cv;
typedef __attribute__((address_space(3))) void*       as3v;

// round-to-nearest-even fp32 -> bf16
static __device__ __forceinline__ u16 f2bf(float f) {
    unsigned u = __builtin_bit_cast(unsigned, f);
    u += 0x7fffu + ((u >> 16) & 1u);
    return (u16)(u >> 16);
}

// ---------------------------------------------------------------- fp32 -> bf16 convert
__global__ __launch_bounds__(256) void cvt_bf16_kernel(
    const float* __restrict__ in, u16* __restrict__ out, int n8)
{
    int i = blockIdx.x * 256 + threadIdx.x;
    if (i >= n8) return;
    const float4* p = (const float4*)in + 2 * (size_t)i;
    float4 a = p[0], b = p[1];
    s8v o;
    o[0] = (short)f2bf(a.x); o[1] = (short)f2bf(a.y);
    o[2] = (short)f2bf(a.z); o[3] = (short)f2bf(a.w);
    o[4] = (short)f2bf(b.x); o[5] = (short)f2bf(b.y);
    o[6] = (short)f2bf(b.z); o[7] = (short)f2bf(b.w);
    ((s8v*)out)[i] = o;
}

// ---------------------------------------------------------------- embedding (bf16 out)
__global__ __launch_bounds__(256) void embed_kernel(
    const int* __restrict__ tok, const float* __restrict__ emb,
    u16* __restrict__ Xb)
{
    int row = blockIdx.x;
    int t = tok[row];
    float4 v = ((const float4*)(emb + (size_t)t * DM))[threadIdx.x];
    ushort4 o;
    o.x = f2bf(v.x); o.y = f2bf(v.y); o.z = f2bf(v.z); o.w = f2bf(v.w);
    ((ushort4*)(Xb + (size_t)row * DM))[threadIdx.x] = o;
}

// ---------------------------------------------------------------- bf16 MFMA GEMM (m97-style)
// C = A[M,K](bf16) * Bt[N,K](bf16)^T.  128x128 tile, BK=32, 256 thr = 4
// waves (2x2), wave tile 64x64 = 4x4 x mfma_f32_16x16x32_bf16.
// Staging: global_load_lds dwordx4 to linear LDS dest; XOR slot-swizzle on
// the per-lane GLOBAL source + on the ds_read address (both-sides, rule #21).
// blockIdx.x = M-tile (fastest): consecutive blocks share the B panel.
// MODE 0: fp32 C0 (ldc0).  MODE 1: in_proj split -> cols<DI fp32 C0[.,DI],
// cols>=DI fp32 C1[.,DI].  MODE 2: fp32 C0 + bf16 Cb (ldc0).
template<int MODE>
__global__ __launch_bounds__(256) void gemm_bb(
    const u16* __restrict__ A, int lda,
    const u16* __restrict__ Bt, int ldb,
    float* __restrict__ C0, float* __restrict__ C1,
    u16* __restrict__ Cb, int ldc0, int K)
{
    __shared__ __align__(16) u16 As[128 * 32];
    __shared__ __align__(16) u16 Bs[128 * 32];

    const int tid  = threadIdx.x;
    const int lane = tid & 63;
    const int wv   = tid >> 6;
    const int bm = blockIdx.x * 128;
    const int bn = blockIdx.y * 128;

    // staging: wave wv rows [wv*32, wv*32+32); lane l -> row wv*32+i*16+(l>>2),
    // LDS slot l&3 holds logical k-slot (l&3)^((l>>3)&3)  (slot ^= (row>>1)&3)
    const int ks = (lane & 3) ^ ((lane >> 3) & 3);
    const int sr = wv * 32 + (lane >> 2);
    const u16* ag0 = A  + (size_t)(bm + sr) * lda + ks * 8;
    const u16* ag1 = ag0 + 16 * (size_t)lda;
    const u16* bg0 = Bt + (size_t)(bn + sr) * ldb + ks * 8;
    const u16* bg1 = bg0 + 16 * (size_t)ldb;
    u16* lA0 = &As[wv * 1024];
    u16* lA1 = &As[wv * 1024 + 512];
    u16* lB0 = &Bs[wv * 1024];
    u16* lB1 = &Bs[wv * 1024 + 512];

    // fragment reads: row wr+m*16+li, logical slot kc stored at kc^((li>>1)&3)
    const int li = lane & 15;
    const int kc = lane >> 4;
    const int wr = (wv >> 1) * 64;
    const int wc = (wv & 1) * 64;
    const int fo = (kc ^ ((li >> 1) & 3)) * 8;

    f32x4 acc[4][4];
#pragma unroll
    for (int m = 0; m < 4; ++m)
#pragma unroll
        for (int n = 0; n < 4; ++n) acc[m][n] = (f32x4)0.f;

    for (int kk = 0; kk < K; kk += 32) {
        __builtin_amdgcn_global_load_lds((as1cv)(ag0 + kk), (as3v)lA0, 16, 0, 0);
        __builtin_amdgcn_global_load_lds((as1cv)(ag1 + kk), (as3v)lA1, 16, 0, 0);
        __builtin_amdgcn_global_load_lds((as1cv)(bg0 + kk), (as3v)lB0, 16, 0, 0);
        __builtin_amdgcn_global_load_lds((as1cv)(bg1 + kk), (as3v)lB1, 16, 0, 0);
        __syncthreads();

        s8v af[4], bf[4];
#pragma unroll
        for (int m = 0; m < 4; ++m)
            af[m] = *(const s8v*)&As[(wr + m * 16 + li) * 32 + fo];
#pragma unroll
        for (int n = 0; n < 4; ++n)
            bf[n] = *(const s8v*)&Bs[(wc + n * 16 + li) * 32 + fo];
#pragma unroll
        for (int m = 0; m < 4; ++m)
#pragma unroll
            for (int n = 0; n < 4; ++n)
                acc[m][n] = __builtin_amdgcn_mfma_f32_16x16x32_bf16(
                    af[m], bf[n], acc[m][n], 0, 0, 0);
        __syncthreads();
    }

    // C row = bm+wr+m*16+kc*4+j, col = bn+wc+n*16+li
#pragma unroll
    for (int m = 0; m < 4; ++m) {
#pragma unroll
        for (int j = 0; j < 4; ++j) {
            int row = bm + wr + m * 16 + kc * 4 + j;
#pragma unroll
            for (int n = 0; n < 4; ++n) {
                int col = bn + wc + n * 16 + li;
                float v = acc[m][n][j];
                if (MODE == 0) {
                    C0[(size_t)row * ldc0 + col] = v;
                } else if (MODE == 1) {
                    if (bn < DI) C0[(size_t)row * DI + col] = v;
                    else         C1[(size_t)row * DI + col - DI] = v;
                } else {
                    C0[(size_t)row * ldc0 + col] = v;
                    Cb[(size_t)row * ldc0 + col] = f2bf(v);
                }
            }
        }
    }
}

// ---------------------------------------------------------------- fp32 SGEMM (small ops)
template<int EPI, bool NGUARD, bool SPLITK>
__global__ __launch_bounds__(256) void sgemm_bt(
    const float* __restrict__ A, int lda,
    const float* __restrict__ Bt, int ldb,
    float* __restrict__ C, int ldc,
    const float* __restrict__ bias,
    int M, int N, int K, int kchunk)
{
    __shared__ float As[16][132];
    __shared__ float Bs[16][132];

    const int tid = threadIdx.x;
    const int bm = blockIdx.y * 128;
    const int bn = blockIdx.x * 128;

    int k0 = 0, kend = K;
    if (SPLITK) {
        k0 = blockIdx.z * kchunk;
        kend = k0 + kchunk; if (kend > K) kend = K;
        C += (size_t)blockIdx.z * (size_t)M * (size_t)ldc;
    }

    const int tx = tid & 15;
    const int ty = tid >> 4;
    const int lr = tid >> 2;
    const int lc = (tid & 3) << 2;

    float acc[8][8];
#pragma unroll
    for (int i = 0; i < 8; ++i)
#pragma unroll
        for (int j = 0; j < 8; ++j) acc[i][j] = 0.f;

    for (int kk = k0; kk < kend; kk += 16) {
#pragma unroll
        for (int p = 0; p < 2; ++p) {
            int r = lr + p * 64;
            float4 v = *(const float4*)(A + (size_t)(bm + r) * lda + kk + lc);
            As[lc + 0][r] = v.x; As[lc + 1][r] = v.y;
            As[lc + 2][r] = v.z; As[lc + 3][r] = v.w;
        }
#pragma unroll
        for (int p = 0; p < 2; ++p) {
            int r = lr + p * 64;
            float4 v = make_float4(0.f, 0.f, 0.f, 0.f);
            if (!NGUARD || (bn + r) < N)
                v = *(const float4*)(Bt + (size_t)(bn + r) * ldb + kk + lc);
            Bs[lc + 0][r] = v.x; Bs[lc + 1][r] = v.y;
            Bs[lc + 2][r] = v.z; Bs[lc + 3][r] = v.w;
        }
        __syncthreads();
#pragma unroll
        for (int k = 0; k < 16; ++k) {
            float4 a0 = *(const float4*)&As[k][ty * 4];
            float4 a1 = *(const float4*)&As[k][64 + ty * 4];
            float4 b0 = *(const float4*)&Bs[k][tx * 4];
            float4 b1 = *(const float4*)&Bs[k][64 + tx * 4];
            float av[8] = {a0.x, a0.y, a0.z, a0.w, a1.x, a1.y, a1.z, a1.w};
            float bv[8] = {b0.x, b0.y, b0.z, b0.w, b1.x, b1.y, b1.z, b1.w};
#pragma unroll
            for (int i = 0; i < 8; ++i)
#pragma unroll
                for (int j = 0; j < 8; ++j)
                    acc[i][j] += av[i] * bv[j];
        }
        __syncthreads();
    }

#pragma unroll
    for (int p = 0; p < 2; ++p) {
#pragma unroll
        for (int ii = 0; ii < 4; ++ii) {
            int row = bm + p * 64 + ty * 4 + ii;
#pragma unroll
            for (int q = 0; q < 2; ++q) {
                int col = bn + q * 64 + tx * 4;
                if (NGUARD && col >= N) continue;
                float4 v;
                float* vp = &v.x;
#pragma unroll
                for (int jj = 0; jj < 4; ++jj) {
                    float x = acc[p * 4 + ii][q * 4 + jj];
                    if (EPI == 1) {
                        x += bias[col + jj];
                        x = (x > 20.f) ? x : log1pf(__expf(x));
                    }
                    vp[jj] = x;
                }
                *(float4*)(C + (size_t)row * ldc + col) = v;
            }
        }
    }
}

// ---------------------------------------------------------------- split-K reduce
__global__ __launch_bounds__(256) void reduce8_kernel(
    const float* __restrict__ part, float* __restrict__ out, int n)
{
    int i = blockIdx.x * 256 + threadIdx.x;
    if (i < n) {
        float s = 0.f;
#pragma unroll
        for (int j = 0; j < 8; ++j) s += part[(size_t)j * n + i];
        out[i] = s;
    }
}

// ---------------------------------------------------------------- conv + SiLU
// U[row,c] = silu(sum_k XZu[row-3+k, c] * w[c,k] + b[c]);  XZu ld = DI
__global__ __launch_bounds__(256) void conv_silu_kernel(
    const float* __restrict__ XZu, const float* __restrict__ cw,
    const float* __restrict__ cb, float* __restrict__ U)
{
    int idx = blockIdx.x * 256 + threadIdx.x;
    int c4 = idx & 511;
    int row = idx >> 9;
    int t = row & (L_SEQ - 1);
    int c = c4 << 2;

    float4 acc;
    acc.x = cb[c]; acc.y = cb[c + 1]; acc.z = cb[c + 2]; acc.w = cb[c + 3];
    float4 w0 = *(const float4*)(cw + (size_t)(c + 0) * 4);
    float4 w1 = *(const float4*)(cw + (size_t)(c + 1) * 4);
    float4 w2 = *(const float4*)(cw + (size_t)(c + 2) * 4);
    float4 w3 = *(const float4*)(cw + (size_t)(c + 3) * 4);
#pragma unroll
    for (int k = 0; k < 4; ++k) {
        int tt = t - 3 + k;
        if (tt >= 0) {
            float4 xv = *(const float4*)(XZu + (size_t)(row - 3 + k) * DI + c);
            acc.x += xv.x * ((&w0.x)[k]);
            acc.y += xv.y * ((&w1.x)[k]);
            acc.z += xv.z * ((&w2.x)[k]);
            acc.w += xv.w * ((&w3.x)[k]);
        }
    }
    acc.x = acc.x / (1.f + __expf(-acc.x));
    acc.y = acc.y / (1.f + __expf(-acc.y));
    acc.z = acc.z / (1.f + __expf(-acc.z));
    acc.w = acc.w / (1.f + __expf(-acc.w));
    *(float4*)(U + (size_t)row * DI + c) = acc;
}

// ---------------------------------------------------------------- SSM scan
// thread = (channel, state); depth-8 prefetch; shfl reduce off the critical
// path; gated bf16 output.
__global__ __launch_bounds__(256) void ssm_scan_kernel(
    const float* __restrict__ U, const float* __restrict__ DELTA,
    const float* __restrict__ DBL, const float* __restrict__ ZF,
    const float* __restrict__ A_log, const float* __restrict__ Dskip,
    u16* __restrict__ Yb)
{
    int tid = threadIdx.x;
    int s = tid & 15;
    int cl = tid >> 4;
    int ch = blockIdx.x * 16 + cl;
    int b = ch >> 11;
    int e = ch & (DI - 1);

    float Ae = -__expf(A_log[(size_t)e * DS + s]);
    float Dk = Dskip[e];
    float h = 0.f;

    const float* up = U     + (size_t)b * L_SEQ * DI + e;
    const float* dp = DELTA + (size_t)b * L_SEQ * DI + e;
    const float* zp = ZF    + (size_t)b * L_SEQ * DI + e;
    const float* bp = DBL   + (size_t)b * L_SEQ * DBLC + DTR + s;
    const float* cp = DBL   + (size_t)b * L_SEQ * DBLC + DTR + DS + s;
    u16* yp = Yb + (size_t)b * L_SEQ * DI + e;

    float u[8], d[8], Bv[8], Cv[8], zv[8];
#pragma unroll
    for (int j = 0; j < 8; ++j) {
        u[j]  = up[(size_t)j * DI];
        d[j]  = dp[(size_t)j * DI];
        Bv[j] = bp[(size_t)j * DBLC];
        Cv[j] = cp[(size_t)j * DBLC];
        zv[j] = zp[(size_t)j * DI];
    }

    for (int t0 = 0; t0 < L_SEQ; t0 += 8) {
        float nu[8], nd[8], nB[8], nC[8], nz[8];
        if (t0 + 8 < L_SEQ) {
#pragma unroll
            for (int j = 0; j < 8; ++j) {
                size_t tt = (size_t)(t0 + 8 + j);
                nu[j] = up[tt * DI];
                nd[j] = dp[tt * DI];
                nB[j] = bp[tt * DBLC];
                nC[j] = cp[tt * DBLC];
                nz[j] = zp[tt * DI];
            }
        } else {
#pragma unroll
            for (int j = 0; j < 8; ++j) { nu[j]=nd[j]=nB[j]=nC[j]=nz[j]=0.f; }
        }
        float pv[8];
#pragma unroll
        for (int j = 0; j < 8; ++j) {
            h = h * __expf(d[j] * Ae) + d[j] * u[j] * Bv[j];
            pv[j] = h * Cv[j];
        }
#pragma unroll
        for (int j = 0; j < 8; ++j) {
            float p = pv[j];
            p += __shfl_xor(p, 1, 16);
            p += __shfl_xor(p, 2, 16);
            p += __shfl_xor(p, 4, 16);
            p += __shfl_xor(p, 8, 16);
            if (s == 0) {
                float z = zv[j];
                float g = z / (1.f + __expf(-z));
                yp[(size_t)(t0 + j) * DI] = f2bf((p + u[j] * Dk) * g);
            }
        }
#pragma unroll
        for (int j = 0; j < 8; ++j) {
            u[j] = nu[j]; d[j] = nd[j]; Bv[j] = nB[j]; Cv[j] = nC[j]; zv[j] = nz[j];
        }
    }
}

// ---------------------------------------------------------------- layernorm (bf16 out)
__global__ __launch_bounds__(256) void layernorm_kernel(
    const float* __restrict__ X, const float* __restrict__ g,
    const float* __restrict__ be, u16* __restrict__ XNb)
{
    __shared__ float red[4];
    int row = blockIdx.x;
    int tid = threadIdx.x;
    float4 v = ((const float4*)(X + (size_t)row * DM))[tid];

    float ssum = v.x + v.y + v.z + v.w;
#pragma unroll
    for (int o = 32; o >= 1; o >>= 1) ssum += __shfl_xor(ssum, o);
    if ((tid & 63) == 0) red[tid >> 6] = ssum;
    __syncthreads();
    float mean = (red[0] + red[1] + red[2] + red[3]) * (1.f / DM);
    __syncthreads();

    float dx = v.x - mean, dy = v.y - mean, dz = v.z - mean, dw = v.w - mean;
    float sq = dx * dx + dy * dy + dz * dz + dw * dw;
#pragma unroll
    for (int o = 32; o >= 1; o >>= 1) sq += __shfl_xor(sq, o);
    if ((tid & 63) == 0) red[tid >> 6] = sq;
    __syncthreads();
    float var = (red[0] + red[1] + red[2] + red[3]) * (1.f / DM);
    float rs = rsqrtf(var + 1e-5f);

    float4 gv = ((const float4*)g)[tid];
    float4 bv = ((const float4*)be)[tid];
    ushort4 o;
    o.x = f2bf(dx * rs * gv.x + bv.x);
    o.y = f2bf(dy * rs * gv.y + bv.y);
    o.z = f2bf(dz * rs * gv.z + bv.z);
    o.w = f2bf(dw * rs * gv.w + bv.w);
    ((ushort4*)(XNb + (size_t)row * DM))[tid] = o;
}

// ---------------------------------------------------------------- launch
extern "C" void kernel_launch(void* const* d_in, const int* in_sizes, int n_in,
                              void* d_out, int out_size, void* d_ws, size_t ws_size,
                              hipStream_t stream)
{
    const int*   tokens = (const int*)d_in[0];
    const float* emb    = (const float*)d_in[1];
    const float* in_w   = (const float*)d_in[2];
    const float* conv_w = (const float*)d_in[3];
    const float* conv_b = (const float*)d_in[4];
    const float* xp_w   = (const float*)d_in[5];
    const float* dt_w   = (const float*)d_in[6];
    const float* dt_b   = (const float*)d_in[7];
    const float* A_log  = (const float*)d_in[8];
    const float* Dskip  = (const float*)d_in[9];
    const float* out_w  = (const float*)d_in[10];
    const float* gamma  = (const float*)d_in[11];
    const float* beta   = (const float*)d_in[12];
    const float* lm_w   = (const float*)d_in[13];
    float* out = (float*)d_out;

    // ---- workspace layout: 43.39M floats = 173.6 MB total (round 1/2 used
    // 186 MB and passed post-timing; round 3's 203 MB diverged -> stay under).
    float* ws = (float*)d_ws;
    size_t off = 0;
    float* X     = ws + off; off += (size_t)BL * DM;        //  4.19M  fp32 LN input
    float* XZu   = ws + off; off += (size_t)BL * DI;        //  8.39M  fp32 u-branch
    float* U     = ws + off; off += (size_t)BL * DI;        //  8.39M  fp32 conv out
    float* ZF    = ws + off; off += (size_t)BL * DI;        //  8.39M  fp32 z-gate
    float* DELTA = ws + off; off += (size_t)BL * DI;        //  8.39M  fp32
    float* DBL   = ws + off; off += (size_t)BL * DBLC;      //  0.39M
    u16* Xb     = (u16*)(ws + off); off += (size_t)BL * DM / 2;      // 2.10M
    u16* wb_in  = (u16*)(ws + off); off += (size_t)2 * DI * DM / 2;  // 2.10M (per-layer)
    u16* wb_out = (u16*)(ws + off); off += (size_t)DM * DI / 2;      // 1.05M (per-layer)
    // aliases (lifetime-checked):
    u16* Yb    = (u16*)XZu;   // scan out; XZu dead after conv_silu of same layer
    u16* wb_lm = (u16*)XZu;   // 65.5 MB over [XZu|U] (67.1 MB); both dead after
                              // layer-2 scan + out_proj (out_proj reads Yb=XZu,
                              // cvt runs after it)
    float* PART = DELTA;      // split-K partials; consumed before dt_proj
                              // overwrites DELTA
    u16* XNb   = Xb;          // LN out; Xb (x input) dead after in_proj layer-2

    embed_kernel<<<BL, 256, 0, stream>>>(tokens, emb, Xb);

    for (int l = 0; l < 2; ++l) {
        const float* cwp = conv_w + (size_t)l * DI * 4;
        const float* cbp = conv_b + (size_t)l * DI;
        const float* xw  = xp_w   + (size_t)l * DBLC * DI;
        const float* dw  = dt_w   + (size_t)l * DI * DTR;
        const float* dbp = dt_b   + (size_t)l * DI;
        const float* alp = A_log  + (size_t)l * DI * DS;
        const float* dkp = Dskip  + (size_t)l * DI;

        // per-layer weight conversion (reused buffers)
        cvt_bf16_kernel<<<(2 * DI * DM / 8 + 255) / 256, 256, 0, stream>>>(
            in_w + (size_t)l * 2 * DI * DM, wb_in, 2 * DI * DM / 8);

        // xz = x @ in_w^T : [4096,4096] K=1024; u-half -> XZu, z-half -> ZF
        gemm_bb<1><<<dim3(32, 32), 256, 0, stream>>>(
            Xb, DM, wb_in, DM, XZu, ZF, nullptr, 0, DM);
        // u = silu(conv(XZu))
        conv_silu_kernel<<<(BL * DI / 4) / 256, 256, 0, stream>>>(XZu, cwp, cbp, U);
        // x_dbl = u @ xp_w^T : [4096,96] fp32 split-K
        sgemm_bt<0, true, true><<<dim3(1, 32, 8), 256, 0, stream>>>(
            U, DI, xw, DI, PART, DBLC, nullptr, BL, DBLC, DI, DI / 8);
        reduce8_kernel<<<(BL * DBLC + 255) / 256, 256, 0, stream>>>(
            PART, DBL, BL * DBLC);
        // delta = softplus(dt @ dt_w^T + dt_b) fp32 (K=64)
        sgemm_bt<1, false, false><<<dim3(16, 32), 256, 0, stream>>>(
            DBL, DBLC, dw, DTR, DELTA, DI, dbp, BL, DI, DTR, 0);
        // scan + D-skip + gating -> bf16 Yb (aliases XZu, dead by now)
        ssm_scan_kernel<<<BL / 16, 256, 0, stream>>>(
            U, DELTA, DBL, ZF, alp, dkp, Yb);
        // out_proj weights, then x = y @ out_w^T : [4096,1024] K=2048
        cvt_bf16_kernel<<<(DM * DI / 8 + 255) / 256, 256, 0, stream>>>(
            out_w + (size_t)l * DM * DI, wb_out, DM * DI / 8);
        gemm_bb<2><<<dim3(32, 8), 256, 0, stream>>>(
            Yb, DI, wb_out, DI, X, nullptr, Xb, DM, DI);
    }

    // lm_head weight conversion into now-dead [XZu|U] space
    cvt_bf16_kernel<<<((size_t)VOCAB * DM / 8 + 255) / 256, 256, 0, stream>>>(
        lm_w, wb_lm, VOCAB * DM / 8);

    layernorm_kernel<<<BL, 256, 0, stream>>>(X, gamma, beta, XNb);

    // logits = xn @ lm_head^T : [4096,32000] K=1024
    gemm_bb<0><<<dim3(32, 250), 256, 0, stream>>>(
        XNb, DM, wb_lm, DM, out, nullptr, nullptr, VOCAB, DM);
}

// Round 5
// 1339.000 us; speedup vs baseline: 5.5345x; 1.5258x over previous
//
#include <hip/hip_runtime.h>
#include <hip/hip_bf16.h>

#define L_SEQ 2048
#define BATCH 2
#define DM    1024          // d_model
#define DI    2048          // d_inner
#define DS    16            // d_state
#define DTR   64            // dt_rank
#define DBLC  96            // dt_rank + 2*d_state
#define VOCAB 32000
#define BL    (BATCH * L_SEQ)   // 4096 tokens
#define NCH   16            // scan chunks
#define CHL   (L_SEQ / NCH) // 128 steps per chunk

typedef unsigned short u16;
typedef short s8v  __attribute__((ext_vector_type(8)));   // 8 bf16
typedef float f32x4 __attribute__((ext_vector_type(4)));

typedef __attribute__((address_space(1))) const void* as1cv;
typedef __attribute__((address_space(3))) void*       as3v;

// round-to-nearest-even fp32 -> bf16
static __device__ __forceinline__ u16 f2bf(float f) {
    unsigned u = __builtin_bit_cast(unsigned, f);
    u += 0x7fffu + ((u >> 16) & 1u);
    return (u16)(u >> 16);
}

// ---------------------------------------------------------------- fp32 -> bf16 convert
__global__ __launch_bounds__(256) void cvt_bf16_kernel(
    const float* __restrict__ in, u16* __restrict__ out, int n8)
{
    int i = blockIdx.x * 256 + threadIdx.x;
    if (i >= n8) return;
    const float4* p = (const float4*)in + 2 * (size_t)i;
    float4 a = p[0], b = p[1];
    s8v o;
    o[0] = (short)f2bf(a.x); o[1] = (short)f2bf(a.y);
    o[2] = (short)f2bf(a.z); o[3] = (short)f2bf(a.w);
    o[4] = (short)f2bf(b.x); o[5] = (short)f2bf(b.y);
    o[6] = (short)f2bf(b.z); o[7] = (short)f2bf(b.w);
    ((s8v*)out)[i] = o;
}

// ---------------------------------------------------------------- embedding (bf16 out)
__global__ __launch_bounds__(256) void embed_kernel(
    const int* __restrict__ tok, const float* __restrict__ emb,
    u16* __restrict__ Xb)
{
    int row = blockIdx.x;
    int t = tok[row];
    float4 v = ((const float4*)(emb + (size_t)t * DM))[threadIdx.x];
    ushort4 o;
    o.x = f2bf(v.x); o.y = f2bf(v.y); o.z = f2bf(v.z); o.w = f2bf(v.w);
    ((ushort4*)(Xb + (size_t)row * DM))[threadIdx.x] = o;
}

// ---------------------------------------------------------------- bf16 MFMA GEMM (m97-style)
// C = A[M,K](bf16) * Bt[N,K](bf16)^T.  128x128 tile, BK=32, 256 thr = 4
// waves (2x2), wave tile 64x64 = 4x4 x mfma_f32_16x16x32_bf16.
// global_load_lds dwordx4 to linear LDS dest; XOR slot-swizzle on the
// per-lane GLOBAL source + the ds_read address (both-sides, rule #21).
// blockIdx.x = M-tile (fastest): consecutive blocks share the B panel.
// MODE 0: fp32 C0.  MODE 1: in_proj split u/z.  MODE 2: fp32 C0 + bf16 Cb.
template<int MODE>
__global__ __launch_bounds__(256) void gemm_bb(
    const u16* __restrict__ A, int lda,
    const u16* __restrict__ Bt, int ldb,
    float* __restrict__ C0, float* __restrict__ C1,
    u16* __restrict__ Cb, int ldc0, int K)
{
    __shared__ __align__(16) u16 As[128 * 32];
    __shared__ __align__(16) u16 Bs[128 * 32];

    const int tid  = threadIdx.x;
    const int lane = tid & 63;
    const int wv   = tid >> 6;
    const int bm = blockIdx.x * 128;
    const int bn = blockIdx.y * 128;

    const int ks = (lane & 3) ^ ((lane >> 3) & 3);
    const int sr = wv * 32 + (lane >> 2);
    const u16* ag0 = A  + (size_t)(bm + sr) * lda + ks * 8;
    const u16* ag1 = ag0 + 16 * (size_t)lda;
    const u16* bg0 = Bt + (size_t)(bn + sr) * ldb + ks * 8;
    const u16* bg1 = bg0 + 16 * (size_t)ldb;
    u16* lA0 = &As[wv * 1024];
    u16* lA1 = &As[wv * 1024 + 512];
    u16* lB0 = &Bs[wv * 1024];
    u16* lB1 = &Bs[wv * 1024 + 512];

    const int li = lane & 15;
    const int kc = lane >> 4;
    const int wr = (wv >> 1) * 64;
    const int wc = (wv & 1) * 64;
    const int fo = (kc ^ ((li >> 1) & 3)) * 8;

    f32x4 acc[4][4];
#pragma unroll
    for (int m = 0; m < 4; ++m)
#pragma unroll
        for (int n = 0; n < 4; ++n) acc[m][n] = (f32x4)0.f;

    for (int kk = 0; kk < K; kk += 32) {
        __builtin_amdgcn_global_load_lds((as1cv)(ag0 + kk), (as3v)lA0, 16, 0, 0);
        __builtin_amdgcn_global_load_lds((as1cv)(ag1 + kk), (as3v)lA1, 16, 0, 0);
        __builtin_amdgcn_global_load_lds((as1cv)(bg0 + kk), (as3v)lB0, 16, 0, 0);
        __builtin_amdgcn_global_load_lds((as1cv)(bg1 + kk), (as3v)lB1, 16, 0, 0);
        __syncthreads();

        s8v af[4], bf[4];
#pragma unroll
        for (int m = 0; m < 4; ++m)
            af[m] = *(const s8v*)&As[(wr + m * 16 + li) * 32 + fo];
#pragma unroll
        for (int n = 0; n < 4; ++n)
            bf[n] = *(const s8v*)&Bs[(wc + n * 16 + li) * 32 + fo];
#pragma unroll
        for (int m = 0; m < 4; ++m)
#pragma unroll
            for (int n = 0; n < 4; ++n)
                acc[m][n] = __builtin_amdgcn_mfma_f32_16x16x32_bf16(
                    af[m], bf[n], acc[m][n], 0, 0, 0);
        __syncthreads();
    }

    // C row = bm+wr+m*16+kc*4+j, col = bn+wc+n*16+li
#pragma unroll
    for (int m = 0; m < 4; ++m) {
#pragma unroll
        for (int j = 0; j < 4; ++j) {
            int row = bm + wr + m * 16 + kc * 4 + j;
#pragma unroll
            for (int n = 0; n < 4; ++n) {
                int col = bn + wc + n * 16 + li;
                float v = acc[m][n][j];
                if (MODE == 0) {
                    C0[(size_t)row * ldc0 + col] = v;
                } else if (MODE == 1) {
                    if (bn < DI) C0[(size_t)row * DI + col] = v;
                    else         C1[(size_t)row * DI + col - DI] = v;
                } else {
                    C0[(size_t)row * ldc0 + col] = v;
                    Cb[(size_t)row * ldc0 + col] = f2bf(v);
                }
            }
        }
    }
}

// ---------------------------------------------------------------- fp32 SGEMM (small ops)
template<int EPI, bool NGUARD, bool SPLITK>
__global__ __launch_bounds__(256) void sgemm_bt(
    const float* __restrict__ A, int lda,
    const float* __restrict__ Bt, int ldb,
    float* __restrict__ C, int ldc,
    const float* __restrict__ bias,
    int M, int N, int K, int kchunk)
{
    __shared__ float As[16][132];
    __shared__ float Bs[16][132];

    const int tid = threadIdx.x;
    const int bm = blockIdx.y * 128;
    const int bn = blockIdx.x * 128;

    int k0 = 0, kend = K;
    if (SPLITK) {
        k0 = blockIdx.z * kchunk;
        kend = k0 + kchunk; if (kend > K) kend = K;
        C += (size_t)blockIdx.z * (size_t)M * (size_t)ldc;
    }

    const int tx = tid & 15;
    const int ty = tid >> 4;
    const int lr = tid >> 2;
    const int lc = (tid & 3) << 2;

    float acc[8][8];
#pragma unroll
    for (int i = 0; i < 8; ++i)
#pragma unroll
        for (int j = 0; j < 8; ++j) acc[i][j] = 0.f;

    for (int kk = k0; kk < kend; kk += 16) {
#pragma unroll
        for (int p = 0; p < 2; ++p) {
            int r = lr + p * 64;
            float4 v = *(const float4*)(A + (size_t)(bm + r) * lda + kk + lc);
            As[lc + 0][r] = v.x; As[lc + 1][r] = v.y;
            As[lc + 2][r] = v.z; As[lc + 3][r] = v.w;
        }
#pragma unroll
        for (int p = 0; p < 2; ++p) {
            int r = lr + p * 64;
            float4 v = make_float4(0.f, 0.f, 0.f, 0.f);
            if (!NGUARD || (bn + r) < N)
                v = *(const float4*)(Bt + (size_t)(bn + r) * ldb + kk + lc);
            Bs[lc + 0][r] = v.x; Bs[lc + 1][r] = v.y;
            Bs[lc + 2][r] = v.z; Bs[lc + 3][r] = v.w;
        }
        __syncthreads();
#pragma unroll
        for (int k = 0; k < 16; ++k) {
            float4 a0 = *(const float4*)&As[k][ty * 4];
            float4 a1 = *(const float4*)&As[k][64 + ty * 4];
            float4 b0 = *(const float4*)&Bs[k][tx * 4];
            float4 b1 = *(const float4*)&Bs[k][64 + tx * 4];
            float av[8] = {a0.x, a0.y, a0.z, a0.w, a1.x, a1.y, a1.z, a1.w};
            float bv[8] = {b0.x, b0.y, b0.z, b0.w, b1.x, b1.y, b1.z, b1.w};
#pragma unroll
            for (int i = 0; i < 8; ++i)
#pragma unroll
                for (int j = 0; j < 8; ++j)
                    acc[i][j] += av[i] * bv[j];
        }
        __syncthreads();
    }

#pragma unroll
    for (int p = 0; p < 2; ++p) {
#pragma unroll
        for (int ii = 0; ii < 4; ++ii) {
            int row = bm + p * 64 + ty * 4 + ii;
#pragma unroll
            for (int q = 0; q < 2; ++q) {
                int col = bn + q * 64 + tx * 4;
                if (NGUARD && col >= N) continue;
                float4 v;
                float* vp = &v.x;
#pragma unroll
                for (int jj = 0; jj < 4; ++jj) {
                    float x = acc[p * 4 + ii][q * 4 + jj];
                    if (EPI == 1) {
                        x += bias[col + jj];
                        x = (x > 20.f) ? x : log1pf(__expf(x));
                    }
                    vp[jj] = x;
                }
                *(float4*)(C + (size_t)row * ldc + col) = v;
            }
        }
    }
}

// ---------------------------------------------------------------- split-K reduce
__global__ __launch_bounds__(256) void reduce8_kernel(
    const float* __restrict__ part, float* __restrict__ out, int n)
{
    int i = blockIdx.x * 256 + threadIdx.x;
    if (i < n) {
        float s = 0.f;
#pragma unroll
        for (int j = 0; j < 8; ++j) s += part[(size_t)j * n + i];
        out[i] = s;
    }
}

// ---------------------------------------------------------------- conv + SiLU
__global__ __launch_bounds__(256) void conv_silu_kernel(
    const float* __restrict__ XZu, const float* __restrict__ cw,
    const float* __restrict__ cb, float* __restrict__ U)
{
    int idx = blockIdx.x * 256 + threadIdx.x;
    int c4 = idx & 511;
    int row = idx >> 9;
    int t = row & (L_SEQ - 1);
    int c = c4 << 2;

    float4 acc;
    acc.x = cb[c]; acc.y = cb[c + 1]; acc.z = cb[c + 2]; acc.w = cb[c + 3];
    float4 w0 = *(const float4*)(cw + (size_t)(c + 0) * 4);
    float4 w1 = *(const float4*)(cw + (size_t)(c + 1) * 4);
    float4 w2 = *(const float4*)(cw + (size_t)(c + 2) * 4);
    float4 w3 = *(const float4*)(cw + (size_t)(c + 3) * 4);
#pragma unroll
    for (int k = 0; k < 4; ++k) {
        int tt = t - 3 + k;
        if (tt >= 0) {
            float4 xv = *(const float4*)(XZu + (size_t)(row - 3 + k) * DI + c);
            acc.x += xv.x * ((&w0.x)[k]);
            acc.y += xv.y * ((&w1.x)[k]);
            acc.z += xv.z * ((&w2.x)[k]);
            acc.w += xv.w * ((&w3.x)[k]);
        }
    }
    acc.x = acc.x / (1.f + __expf(-acc.x));
    acc.y = acc.y / (1.f + __expf(-acc.y));
    acc.z = acc.z / (1.f + __expf(-acc.z));
    acc.w = acc.w / (1.f + __expf(-acc.w));
    *(float4*)(U + (size_t)row * DI + c) = acc;
}

// ---------------------------------------------------------------- chunked parallel scan
// Linear recurrence h_t = a_t h_{t-1} + b_t, a_t = exp(d_t*A), b_t = d_t u_t B_t.
// Pass 1: per-(b,e,s,chunk) transfer function (P = prod a, S).
// Pass 2: serial combine over NCH chunks -> h_start per chunk.
// Pass 3: rerun recurrence per chunk from h_start, emit gated bf16 y.
// Block = 16 channels x 16 states; grid = (b, e-group, chunk).

__global__ __launch_bounds__(256) void scan_part1(
    const float* __restrict__ U, const float* __restrict__ DELTA,
    const float* __restrict__ DBL, const float* __restrict__ A_log,
    float* __restrict__ PS)
{
    int tid = threadIdx.x;
    int s = tid & 15;
    int cl = tid >> 4;
    int gid = blockIdx.x;              // chunk fastest
    int chunk = gid & (NCH - 1);
    int eg = (gid >> 4) & (DI / 16 - 1);
    int b = gid >> 11;                 // gid / (128*16)
    int e = eg * 16 + cl;

    float Ae = -__expf(A_log[(size_t)e * DS + s]);
    const float* up = U     + (size_t)b * L_SEQ * DI + e;
    const float* dp = DELTA + (size_t)b * L_SEQ * DI + e;
    const float* bp = DBL   + (size_t)b * L_SEQ * DBLC + DTR + s;
    const int t0 = chunk * CHL;

    float P = 1.f, S = 0.f;
    for (int i = 0; i < CHL; i += 8) {
        float d[8], u[8], Bv[8];
#pragma unroll
        for (int j = 0; j < 8; ++j) {
            size_t t = (size_t)(t0 + i + j);
            d[j]  = dp[t * DI];
            u[j]  = up[t * DI];
            Bv[j] = bp[t * DBLC];
        }
#pragma unroll
        for (int j = 0; j < 8; ++j) {
            float a = __expf(d[j] * Ae);
            P *= a;
            S = S * a + d[j] * u[j] * Bv[j];
        }
    }
    size_t idx = (((size_t)b * DI + e) * DS + s) * NCH + chunk;
    ((float2*)PS)[idx] = make_float2(P, S);
}

__global__ __launch_bounds__(256) void scan_part2(
    const float* __restrict__ PS, float* __restrict__ HST)
{
    size_t i = (size_t)blockIdx.x * 256 + threadIdx.x;   // (b,e,s) flat, 65536
    const float2* ps = (const float2*)PS + i * NCH;
    float* hs = HST + i * NCH;
    float h = 0.f;
#pragma unroll
    for (int c = 0; c < NCH; ++c) {
        hs[c] = h;
        float2 v = ps[c];
        h = v.x * h + v.y;
    }
}

__global__ __launch_bounds__(256) void scan_part3(
    const float* __restrict__ U, const float* __restrict__ DELTA,
    const float* __restrict__ DBL, const float* __restrict__ ZF,
    const float* __restrict__ A_log, const float* __restrict__ Dskip,
    const float* __restrict__ HST, u16* __restrict__ Yb)
{
    int tid = threadIdx.x;
    int s = tid & 15;
    int cl = tid >> 4;
    int gid = blockIdx.x;
    int chunk = gid & (NCH - 1);
    int eg = (gid >> 4) & (DI / 16 - 1);
    int b = gid >> 11;
    int e = eg * 16 + cl;

    float Ae = -__expf(A_log[(size_t)e * DS + s]);
    float Dk = Dskip[e];
    const float* up = U     + (size_t)b * L_SEQ * DI + e;
    const float* dp = DELTA + (size_t)b * L_SEQ * DI + e;
    const float* zp = ZF    + (size_t)b * L_SEQ * DI + e;
    const float* bp = DBL   + (size_t)b * L_SEQ * DBLC + DTR + s;
    const float* cp = DBL   + (size_t)b * L_SEQ * DBLC + DTR + DS + s;
    u16* yp = Yb + (size_t)b * L_SEQ * DI + e;
    const int t0 = chunk * CHL;

    float h = HST[(((size_t)b * DI + e) * DS + s) * NCH + chunk];

    for (int i = 0; i < CHL; i += 8) {
        float d[8], u[8], Bv[8], Cv[8], zv[8];
#pragma unroll
        for (int j = 0; j < 8; ++j) {
            size_t t = (size_t)(t0 + i + j);
            d[j]  = dp[t * DI];
            u[j]  = up[t * DI];
            Bv[j] = bp[t * DBLC];
            Cv[j] = cp[t * DBLC];
            zv[j] = zp[t * DI];
        }
        float pv[8];
#pragma unroll
        for (int j = 0; j < 8; ++j) {
            float a = __expf(d[j] * Ae);
            h = a * h + d[j] * u[j] * Bv[j];
            pv[j] = h * Cv[j];
        }
#pragma unroll
        for (int j = 0; j < 8; ++j) {
            float p = pv[j];
            p += __shfl_xor(p, 1, 16);
            p += __shfl_xor(p, 2, 16);
            p += __shfl_xor(p, 4, 16);
            p += __shfl_xor(p, 8, 16);
            if (s == 0) {
                float z = zv[j];
                float g = z / (1.f + __expf(-z));
                yp[(size_t)(t0 + i + j) * DI] = f2bf((p + u[j] * Dk) * g);
            }
        }
    }
}

// ---------------------------------------------------------------- layernorm (bf16 out)
__global__ __launch_bounds__(256) void layernorm_kernel(
    const float* __restrict__ X, const float* __restrict__ g,
    const float* __restrict__ be, u16* __restrict__ XNb)
{
    __shared__ float red[4];
    int row = blockIdx.x;
    int tid = threadIdx.x;
    float4 v = ((const float4*)(X + (size_t)row * DM))[tid];

    float ssum = v.x + v.y + v.z + v.w;
#pragma unroll
    for (int o = 32; o >= 1; o >>= 1) ssum += __shfl_xor(ssum, o);
    if ((tid & 63) == 0) red[tid >> 6] = ssum;
    __syncthreads();
    float mean = (red[0] + red[1] + red[2] + red[3]) * (1.f / DM);
    __syncthreads();

    float dx = v.x - mean, dy = v.y - mean, dz = v.z - mean, dw = v.w - mean;
    float sq = dx * dx + dy * dy + dz * dz + dw * dw;
#pragma unroll
    for (int o = 32; o >= 1; o >>= 1) sq += __shfl_xor(sq, o);
    if ((tid & 63) == 0) red[tid >> 6] = sq;
    __syncthreads();
    float var = (red[0] + red[1] + red[2] + red[3]) * (1.f / DM);
    float rs = rsqrtf(var + 1e-5f);

    float4 gv = ((const float4*)g)[tid];
    float4 bv = ((const float4*)be)[tid];
    ushort4 o;
    o.x = f2bf(dx * rs * gv.x + bv.x);
    o.y = f2bf(dy * rs * gv.y + bv.y);
    o.z = f2bf(dz * rs * gv.z + bv.z);
    o.w = f2bf(dw * rs * gv.w + bv.w);
    ((ushort4*)(XNb + (size_t)row * DM))[tid] = o;
}

// ---------------------------------------------------------------- launch
extern "C" void kernel_launch(void* const* d_in, const int* in_sizes, int n_in,
                              void* d_out, int out_size, void* d_ws, size_t ws_size,
                              hipStream_t stream)
{
    const int*   tokens = (const int*)d_in[0];
    const float* emb    = (const float*)d_in[1];
    const float* in_w   = (const float*)d_in[2];
    const float* conv_w = (const float*)d_in[3];
    const float* conv_b = (const float*)d_in[4];
    const float* xp_w   = (const float*)d_in[5];
    const float* dt_w   = (const float*)d_in[6];
    const float* dt_b   = (const float*)d_in[7];
    const float* A_log  = (const float*)d_in[8];
    const float* Dskip  = (const float*)d_in[9];
    const float* out_w  = (const float*)d_in[10];
    const float* gamma  = (const float*)d_in[11];
    const float* beta   = (const float*)d_in[12];
    const float* lm_w   = (const float*)d_in[13];
    float* out = (float*)d_out;

    // ---- workspace: 43.39M floats = 173.6 MB (round-4-proven size).
    float* ws = (float*)d_ws;
    size_t off = 0;
    float* X     = ws + off; off += (size_t)BL * DM;        //  4.19M  fp32 LN input
    float* XZu   = ws + off; off += (size_t)BL * DI;        //  8.39M
    float* U     = ws + off; off += (size_t)BL * DI;        //  8.39M
    float* ZF    = ws + off; off += (size_t)BL * DI;        //  8.39M
    float* DELTA = ws + off; off += (size_t)BL * DI;        //  8.39M
    float* DBL   = ws + off; off += (size_t)BL * DBLC;      //  0.39M
    u16* Xb     = (u16*)(ws + off); off += (size_t)BL * DM / 2;      // 2.10M
    u16* wb_in  = (u16*)(ws + off); off += (size_t)2 * DI * DM / 2;  // 2.10M
    u16* wb_out = (u16*)(ws + off); off += (size_t)DM * DI / 2;      // 1.05M
    // aliases (lifetime-checked):
    u16* Yb    = (u16*)XZu;   // scan out; XZu dead after conv_silu
    u16* wb_lm = (u16*)XZu;   // over [XZu|U]; dead after layer-2 out_proj
    float* PART = DELTA;      // split-K partials; consumed before dt_proj
    u16* XNb   = Xb;          // LN out; Xb dead after layer-2 in_proj
    float* PS  = X;           // scan chunk (P,S): 2.10M fl; X dead during scans
    float* HST = X + 2 * (size_t)BL * DI * DS * NCH / L_SEQ; // +2.10M fl? see below
    // PS needs BL/L_SEQ*... : entries = BATCH*DI*DS*NCH = 1.05M -> 2.10M floats.
    // HST = 1.05M floats. PS+HST = 3.15M <= X's 4.19M floats.
    HST = X + (size_t)2 * BATCH * DI * DS * NCH;  // exact: 2*1048576 floats in

    embed_kernel<<<BL, 256, 0, stream>>>(tokens, emb, Xb);

    const int SCAN_GRID = BATCH * (DI / 16) * NCH;  // 4096 blocks

    for (int l = 0; l < 2; ++l) {
        const float* cwp = conv_w + (size_t)l * DI * 4;
        const float* cbp = conv_b + (size_t)l * DI;
        const float* xw  = xp_w   + (size_t)l * DBLC * DI;
        const float* dw  = dt_w   + (size_t)l * DI * DTR;
        const float* dbp = dt_b   + (size_t)l * DI;
        const float* alp = A_log  + (size_t)l * DI * DS;
        const float* dkp = Dskip  + (size_t)l * DI;

        cvt_bf16_kernel<<<(2 * DI * DM / 8 + 255) / 256, 256, 0, stream>>>(
            in_w + (size_t)l * 2 * DI * DM, wb_in, 2 * DI * DM / 8);

        // xz = x @ in_w^T : [4096,4096] K=1024; u-half -> XZu, z-half -> ZF
        gemm_bb<1><<<dim3(32, 32), 256, 0, stream>>>(
            Xb, DM, wb_in, DM, XZu, ZF, nullptr, 0, DM);
        // u = silu(conv(XZu))
        conv_silu_kernel<<<(BL * DI / 4) / 256, 256, 0, stream>>>(XZu, cwp, cbp, U);
        // x_dbl = u @ xp_w^T : [4096,96] fp32 split-K
        sgemm_bt<0, true, true><<<dim3(1, 32, 8), 256, 0, stream>>>(
            U, DI, xw, DI, PART, DBLC, nullptr, BL, DBLC, DI, DI / 8);
        reduce8_kernel<<<(BL * DBLC + 255) / 256, 256, 0, stream>>>(
            PART, DBL, BL * DBLC);
        // delta = softplus(dt @ dt_w^T + dt_b) fp32 (K=64)
        sgemm_bt<1, false, false><<<dim3(16, 32), 256, 0, stream>>>(
            DBL, DBLC, dw, DTR, DELTA, DI, dbp, BL, DI, DTR, 0);
        // chunked parallel scan -> bf16 Yb (aliases XZu)
        scan_part1<<<SCAN_GRID, 256, 0, stream>>>(U, DELTA, DBL, alp, PS);
        scan_part2<<<BATCH * DI * DS / 256, 256, 0, stream>>>(PS, HST);
        scan_part3<<<SCAN_GRID, 256, 0, stream>>>(
            U, DELTA, DBL, ZF, alp, dkp, HST, Yb);
        // out_proj
        cvt_bf16_kernel<<<(DM * DI / 8 + 255) / 256, 256, 0, stream>>>(
            out_w + (size_t)l * DM * DI, wb_out, DM * DI / 8);
        gemm_bb<2><<<dim3(32, 8), 256, 0, stream>>>(
            Yb, DI, wb_out, DI, X, nullptr, Xb, DM, DI);
    }

    cvt_bf16_kernel<<<((size_t)VOCAB * DM / 8 + 255) / 256, 256, 0, stream>>>(
        lm_w, wb_lm, VOCAB * DM / 8);

    layernorm_kernel<<<BL, 256, 0, stream>>>(X, gamma, beta, XNb);

    // logits = xn @ lm_head^T : [4096,32000] K=1024
    gemm_bb<0><<<dim3(32, 250), 256, 0, stream>>>(
        XNb, DM, wb_lm, DM, out, nullptr, nullptr, VOCAB, DM);
}